// Round 1
// baseline (239.102 us; speedup 1.0000x reference)
//
#include <hip/hip_runtime.h>

typedef unsigned long long u64;
typedef unsigned int u32;

// ---------------- packed weights / folded BN params (device globals) --------
__device__ u32 g_w1b[32];                 // 9 taps in low bits
__device__ float g_b1[32], g_inv1[32], g_t1[32];
__device__ u32 g_w2b[64 * 3];             // [c][k], bit = cin (0..31)
__device__ float g_b2[64], g_inv2[64], g_t2[64];
__device__ u64 g_w3b[128 * 3];            // [c][k], bit = cin (0..63)
__device__ float g_b3[128], g_inv3[128], g_t3[128];
__device__ u64 g_w4b[128 * 6 * 2];        // [c][h][hi], bit l = cin hi*64+l
__device__ float g_b4[128], g_inv4[128], g_t4[128];
__device__ u64 g_wfcb[6 * 32];            // [j][k]: w=k%16, hi=k/16, bit l -> i=(hi*64+l)*16+w
__device__ float g_bfc[6];

struct Ptrs { const float* p[27]; };

// exact f32 op order of the np reference: y = ((S + b) * inv) + t, no FMA
__device__ __forceinline__ int sgnbit(int S, float b, float inv, float t) {
  float hv = __fadd_rn((float)S, b);
  float y = __fadd_rn(__fmul_rn(hv, inv), t);
  return y > 0.0f;
}

__device__ __forceinline__ void bn_fold(float b, float g, float be, float m, float v,
                                        float* ob, float* oinv, float* ot) {
  double iv = (double)g * (1.0 / sqrt((double)v + 1e-5));
  float invf = (float)iv;
  *ob = b;
  *oinv = invf;
  *ot = __fadd_rn(be, -__fmul_rn(m, invf));
}

// -------------------------- weight prepack ---------------------------------
__global__ __launch_bounds__(256) void prepack_kernel(Ptrs P) {
  int gid = blockIdx.x * 256 + threadIdx.x;
  if (gid < 32) {                                   // w1 bits
    int c = gid;
    u32 b = 0;
    for (int k = 0; k < 9; ++k)
      if (P.p[1][c * 9 + k] > 0.0f) b |= (1u << k);
    g_w1b[c] = b;
  } else if (gid < 224) {                           // w2 bits
    int idx = gid - 32;
    int c = idx / 3, k = idx % 3;
    u32 b = 0;
    for (int cin = 0; cin < 32; ++cin)
      if (P.p[7][(c * 32 + cin) * 3 + k] > 0.0f) b |= (1u << cin);
    g_w2b[c * 3 + k] = b;
  } else if (gid < 608) {                           // w3 bits
    int idx = gid - 224;
    int c = idx / 3, k = idx % 3;
    u64 b = 0;
    for (int cin = 0; cin < 64; ++cin)
      if (P.p[13][(c * 64 + cin) * 3 + k] > 0.0f) b |= (1ull << cin);
    g_w3b[c * 3 + k] = b;
  } else if (gid < 2144) {                          // w4 bits
    int idx = gid - 608;
    int c = idx / 12, r = idx % 12, h = r >> 1, hi = r & 1;
    u64 b = 0;
    for (int l = 0; l < 64; ++l) {
      int cin = hi * 64 + l;
      if (P.p[19][(c * 128 + cin) * 6 + h] > 0.0f) b |= (1ull << l);
    }
    g_w4b[(c * 6 + h) * 2 + hi] = b;
  } else if (gid < 2336) {                          // wfc bits
    int idx = gid - 2144;
    int j = idx / 32, k = idx % 32;
    int w = k & 15, hi = k >> 4;
    u64 b = 0;
    for (int l = 0; l < 64; ++l) {
      int i = (hi * 64 + l) * 16 + w;
      if (P.p[25][j * 2048 + i] > 0.0f) b |= (1ull << l);
    }
    g_wfcb[j * 32 + k] = b;
  } else if (gid < 2368) {                          // BN fold layer 1
    int c = gid - 2336;
    bn_fold(P.p[2][c], P.p[3][c], P.p[4][c], P.p[5][c], P.p[6][c],
            &g_b1[c], &g_inv1[c], &g_t1[c]);
  } else if (gid < 2432) {                          // layer 2
    int c = gid - 2368;
    bn_fold(P.p[8][c], P.p[9][c], P.p[10][c], P.p[11][c], P.p[12][c],
            &g_b2[c], &g_inv2[c], &g_t2[c]);
  } else if (gid < 2560) {                          // layer 3
    int c = gid - 2432;
    bn_fold(P.p[14][c], P.p[15][c], P.p[16][c], P.p[17][c], P.p[18][c],
            &g_b3[c], &g_inv3[c], &g_t3[c]);
  } else if (gid < 2688) {                          // layer 4
    int c = gid - 2560;
    bn_fold(P.p[20][c], P.p[21][c], P.p[22][c], P.p[23][c], P.p[24][c],
            &g_b4[c], &g_inv4[c], &g_t4[c]);
  } else if (gid < 2694) {                          // bfc
    int c = gid - 2688;
    g_bfc[c] = P.p[26][c];
  }
}

// ----------------------- fused binary network ------------------------------
// one block per image; activations bit-packed in LDS; ballot packs channels
__global__ __launch_bounds__(256) void fused_kernel(const float* __restrict__ x,
                                                    float* __restrict__ out) {
  const int n = blockIdx.x;
  const int tid = threadIdx.x;
  const int lane = tid & 63;
  const int wave = tid >> 6;
  const float* xi = x + (size_t)n * 768;

  __shared__ u64 xb[12];       // input sign bits [h][w] row-major, 6*128 bits
  __shared__ u32 c1s[384];     // conv1 out [h][w'] (h*64+w'), bit = channel
  __shared__ u32 p1s[192];     // pooled    [h][w] (h*32+w)
  __shared__ u64 c2s[192];     // conv2 out [h][w] (h*32+w), bit = channel
  __shared__ u64 c3s[384];     // conv3 out (h*32+w)*2+half
  __shared__ u64 p3s[192];     // pooled    (h*16+w)*2+half
  __shared__ u64 c4s[32];      // conv4 out w*2+half
  __shared__ int fcacc[6];

  if (tid < 6) fcacc[tid] = 0;

  // ---- stage A: binarize input ----
  #pragma unroll
  for (int base = 0; base < 768; base += 256) {
    int idx = base + tid;                    // lane == bit position in word
    float v = xi[idx];
    u64 m = __ballot(v > 0.0f);
    if (lane == 0) xb[idx >> 6] = m;
  }
  __syncthreads();

  // ---- conv1 (1->32, k=9, s=2, pad 4) + sign ----
  {
    const int c = lane & 31;
    const int sub = lane >> 5;
    const u32 wv = g_w1b[c];
    const float bb = g_b1[c], inv = g_inv1[c], tt = g_t1[c];
    for (int it = 0; it < 48; ++it) {
      int p = it * 8 + wave * 2 + sub;       // 0..383 : h*64 + w'
      int h = p >> 6, wp = p & 63;
      u64 rlo = xb[h * 2], rhi = xb[h * 2 + 1];
      int p0 = 2 * wp - 4;
      u32 win = 0, vm = 0;
      #pragma unroll
      for (int k = 0; k < 9; ++k) {
        int pos = p0 + k;
        if (pos >= 0 && pos < 128) {
          vm |= (1u << k);
          u64 word = (pos < 64) ? rlo : rhi;
          if ((word >> (pos & 63)) & 1u) win |= (1u << k);
        }
      }
      int S = __popc(vm) - 2 * __popc((win ^ wv) & vm);
      u64 m = __ballot(sgnbit(S, bb, inv, tt));
      if (lane == 0) { c1s[p] = (u32)m; c1s[p + 1] = (u32)(m >> 32); }
    }
  }
  __syncthreads();

  // ---- maxpool (1,2): sign-max == OR ----
  if (tid < 192) {
    int h = tid >> 5, w = tid & 31;
    p1s[tid] = c1s[h * 64 + 2 * w] | c1s[h * 64 + 2 * w + 1];
  }
  __syncthreads();

  // ---- conv2 (32->64, k=3, pad 1) + sign ----
  {
    const int c = lane;
    const u32 w0 = g_w2b[c * 3 + 0], w1 = g_w2b[c * 3 + 1], w2 = g_w2b[c * 3 + 2];
    const float bb = g_b2[c], inv = g_inv2[c], tt = g_t2[c];
    for (int it = 0; it < 48; ++it) {
      int p = it * 4 + wave;                 // 0..191 : h*32 + w
      int w = p & 31;
      int S = 32 - 2 * __popc(p1s[p] ^ w1);
      if (w > 0)  S += 32 - 2 * __popc(p1s[p - 1] ^ w0);
      if (w < 31) S += 32 - 2 * __popc(p1s[p + 1] ^ w2);
      u64 m = __ballot(sgnbit(S, bb, inv, tt));
      if (lane == 0) c2s[p] = m;
    }
  }
  __syncthreads();

  // ---- conv3 (64->128, k=3, pad 1) + sign ----
  {
    const u64 wl0 = g_w3b[lane * 3 + 0], wl1 = g_w3b[lane * 3 + 1], wl2 = g_w3b[lane * 3 + 2];
    const u64 wh0 = g_w3b[(64 + lane) * 3 + 0], wh1 = g_w3b[(64 + lane) * 3 + 1], wh2 = g_w3b[(64 + lane) * 3 + 2];
    const float b0 = g_b3[lane], i0 = g_inv3[lane], t0 = g_t3[lane];
    const float b1 = g_b3[64 + lane], i1 = g_inv3[64 + lane], t1 = g_t3[64 + lane];
    for (int it = 0; it < 48; ++it) {
      int p = it * 4 + wave;
      int w = p & 31;
      u64 cc = c2s[p];
      int S0 = 64 - 2 * __popcll(cc ^ wl1);
      int S1 = 64 - 2 * __popcll(cc ^ wh1);
      if (w > 0) {
        u64 cl = c2s[p - 1];
        S0 += 64 - 2 * __popcll(cl ^ wl0);
        S1 += 64 - 2 * __popcll(cl ^ wh0);
      }
      if (w < 31) {
        u64 cr = c2s[p + 1];
        S0 += 64 - 2 * __popcll(cr ^ wl2);
        S1 += 64 - 2 * __popcll(cr ^ wh2);
      }
      u64 m0 = __ballot(sgnbit(S0, b0, i0, t0));
      u64 m1 = __ballot(sgnbit(S1, b1, i1, t1));
      if (lane == 0) { c3s[p * 2] = m0; c3s[p * 2 + 1] = m1; }
    }
  }
  __syncthreads();

  // ---- maxpool (1,2) ----
  if (tid < 192) {
    int h = tid / 32, r = tid % 32, w = r >> 1, hf = r & 1;
    p3s[(h * 16 + w) * 2 + hf] =
        c3s[(h * 32 + 2 * w) * 2 + hf] | c3s[(h * 32 + 2 * w + 1) * 2 + hf];
  }
  __syncthreads();

  // ---- conv4 (128->128, k=(6,1)) + sign ----
  {
    const float b0 = g_b4[lane], i0 = g_inv4[lane], t0 = g_t4[lane];
    const float b1 = g_b4[64 + lane], i1 = g_inv4[64 + lane], t1 = g_t4[64 + lane];
    for (int it = 0; it < 4; ++it) {
      int w = it * 4 + wave;
      int acc0 = 0, acc1 = 0;
      #pragma unroll
      for (int h = 0; h < 6; ++h) {
        u64 aL = p3s[(h * 16 + w) * 2];
        u64 aH = p3s[(h * 16 + w) * 2 + 1];
        acc0 += __popcll(aL ^ g_w4b[(lane * 6 + h) * 2]) +
                __popcll(aH ^ g_w4b[(lane * 6 + h) * 2 + 1]);
        acc1 += __popcll(aL ^ g_w4b[((64 + lane) * 6 + h) * 2]) +
                __popcll(aH ^ g_w4b[((64 + lane) * 6 + h) * 2 + 1]);
      }
      u64 m0 = __ballot(sgnbit(768 - 2 * acc0, b0, i0, t0));
      u64 m1 = __ballot(sgnbit(768 - 2 * acc1, b1, i1, t1));
      if (lane == 0) { c4s[w * 2] = m0; c4s[w * 2 + 1] = m1; }
    }
  }
  __syncthreads();

  // ---- FC: sign(h) . sign(wfc)^T + bfc ----
  if (tid < 192) {
    int j = tid >> 5, k = tid & 31;
    int w = k & 15, hf = k >> 4;
    int pc = __popcll(c4s[w * 2 + hf] ^ g_wfcb[j * 32 + k]);
    atomicAdd(&fcacc[j], pc);
  }
  __syncthreads();
  if (tid < 6) {
    out[(size_t)n * 6 + tid] =
        __fadd_rn((float)(2048 - 2 * fcacc[tid]), g_bfc[tid]);
  }
}

// ------------------------------ launch --------------------------------------
extern "C" void kernel_launch(void* const* d_in, const int* in_sizes, int n_in,
                              void* d_out, int out_size, void* d_ws, size_t ws_size,
                              hipStream_t stream) {
  (void)d_ws; (void)ws_size; (void)n_in;
  Ptrs P;
  for (int i = 0; i < 27; ++i) P.p[i] = (const float*)d_in[i];

  hipLaunchKernelGGL(prepack_kernel, dim3(11), dim3(256), 0, stream, P);

  const float* x = (const float*)d_in[0];
  float* out = (float*)d_out;
  int B = in_sizes[0] / 768;                 // 4096
  hipLaunchKernelGGL(fused_kernel, dim3(B), dim3(256), 0, stream, x, out);
}

// Round 2
// 129.518 us; speedup vs baseline: 1.8461x; 1.8461x over previous
//
#include <hip/hip_runtime.h>

typedef unsigned long long u64;
typedef unsigned int u32;

// ---------------- packed weights / integer thresholds (device globals) ------
__device__ u32 g_w1b[32];                 // 9 taps in low bits
__device__ u32 g_w2b[64 * 3];             // [c][k], bit = cin (0..31)
__device__ u64 g_w3b[128 * 3];            // [c][k], bit = cin (0..63)
__device__ u64 g_w4b[128 * 6 * 2];        // [c][h][hi], bit l = cin hi*64+l
__device__ u64 g_wfcb[6 * 32];            // [j][k]: w=k%16, hi=k/16, bit l -> i=(hi*64+l)*16+w
__device__ float g_bfc[6];

__device__ int g_s1[32], g_s2[64], g_s3[128], g_s4[128];   // integer S-thresholds
__device__ u64 g_flip1, g_flip2, g_flip3[2], g_flip4[2];   // per-layer ballot flip masks

struct Ptrs { const float* p[27]; };

// exact f32 op order of the np reference: y = ((S + b) * inv) + t, no FMA
__device__ __forceinline__ int predS(int S, float b, float inv, float t) {
  float hv = __fadd_rn((float)S, b);
  float y = __fadd_rn(__fmul_rn(hv, inv), t);
  return y > 0.0f;
}

__device__ __forceinline__ void bn_fold(float b, float g, float be, float m, float v,
                                        float* ob, float* oinv, float* ot) {
  double iv = (double)g * (1.0 / sqrt((double)v + 1e-5));
  float invf = (float)iv;
  *ob = b;
  *oinv = invf;
  *ot = __fadd_rn(be, -__fmul_rn(m, invf));
}

// Find smallest integer smin with pred(S) == (S >= smin) (flip=0), or the
// complemented form (flip=1) when the affine map is decreasing in S.
__device__ __forceinline__ void find_thr(float bias, float g, float be, float m, float v,
                                         int* smin, int* flip) {
  float b, inv, t;
  bn_fold(bias, g, be, m, v, &b, &inv, &t);
  int pl = predS(-2048, b, inv, t), ph = predS(2048, b, inv, t);
  if (pl && ph) { *smin = -4096; *flip = 0; }
  else if (!pl && !ph) { *smin = 4096; *flip = 0; }
  else if (!pl && ph) {            // increasing: pred = S >= smin
    int lo = -2048, hi = 2048;
    while (hi - lo > 1) { int md = (lo + hi) >> 1; if (predS(md, b, inv, t)) hi = md; else lo = md; }
    *smin = hi; *flip = 0;
  } else {                         // decreasing: !pred = S >= smax+1
    int lo = -2048, hi = 2048;
    while (hi - lo > 1) { int md = (lo + hi) >> 1; if (predS(md, b, inv, t)) lo = md; else hi = md; }
    *smin = lo + 1; *flip = 1;
  }
}

// -------------------------- weight prepack ---------------------------------
__global__ __launch_bounds__(256) void prepack_kernel(Ptrs P) {
  int tid = threadIdx.x;
  int gid = blockIdx.x * 256 + tid;
  if (gid < 32) {                                   // L1 thresholds (block0 wave0)
    int c = gid, smin, flip;
    find_thr(P.p[2][c], P.p[3][c], P.p[4][c], P.p[5][c], P.p[6][c], &smin, &flip);
    g_s1[c] = smin;
    u64 fl = __ballot(flip != 0);
    if (c == 0) g_flip1 = (fl & 0xFFFFFFFFULL) | (fl << 32);
  } else if (gid >= 64 && gid < 128) {              // L2 thresholds (wave1)
    int c = gid - 64, smin, flip;
    find_thr(P.p[8][c], P.p[9][c], P.p[10][c], P.p[11][c], P.p[12][c], &smin, &flip);
    g_s2[c] = smin;
    u64 fl = __ballot(flip != 0);
    if (c == 0) g_flip2 = fl;
  } else if (gid >= 128 && gid < 256) {             // L3 thresholds (waves 2,3)
    int c = gid - 128, smin, flip;
    find_thr(P.p[14][c], P.p[15][c], P.p[16][c], P.p[17][c], P.p[18][c], &smin, &flip);
    g_s3[c] = smin;
    u64 fl = __ballot(flip != 0);
    if ((c & 63) == 0) g_flip3[c >> 6] = fl;
  } else if (gid >= 256 && gid < 384) {             // L4 thresholds (block1 waves 0,1)
    int c = gid - 256, smin, flip;
    find_thr(P.p[20][c], P.p[21][c], P.p[22][c], P.p[23][c], P.p[24][c], &smin, &flip);
    g_s4[c] = smin;
    u64 fl = __ballot(flip != 0);
    if ((c & 63) == 0) g_flip4[c >> 6] = fl;
  } else if (gid >= 384 && gid < 416) {             // w1 bits
    int c = gid - 384;
    u32 b = 0;
    for (int k = 0; k < 9; ++k)
      if (P.p[1][c * 9 + k] > 0.0f) b |= (1u << k);
    g_w1b[c] = b;
  } else if (gid >= 416 && gid < 422) {             // bfc
    g_bfc[gid - 416] = P.p[26][gid - 416];
  } else if (gid >= 512 && gid < 704) {             // w2 bits
    int idx = gid - 512;
    int c = idx / 3, k = idx % 3;
    u32 b = 0;
    for (int cin = 0; cin < 32; ++cin)
      if (P.p[7][(c * 32 + cin) * 3 + k] > 0.0f) b |= (1u << cin);
    g_w2b[c * 3 + k] = b;
  } else if (gid >= 704 && gid < 1088) {            // w3 bits
    int idx = gid - 704;
    int c = idx / 3, k = idx % 3;
    u64 b = 0;
    for (int cin = 0; cin < 64; ++cin)
      if (P.p[13][(c * 64 + cin) * 3 + k] > 0.0f) b |= (1ull << cin);
    g_w3b[c * 3 + k] = b;
  } else if (gid >= 1088 && gid < 2624) {           // w4 bits
    int idx = gid - 1088;
    int c = idx / 12, r = idx % 12, h = r >> 1, hi = r & 1;
    u64 b = 0;
    for (int l = 0; l < 64; ++l) {
      int cin = hi * 64 + l;
      if (P.p[19][(c * 128 + cin) * 6 + h] > 0.0f) b |= (1ull << l);
    }
    g_w4b[(c * 6 + h) * 2 + hi] = b;
  } else if (gid >= 2624 && gid < 2816) {           // wfc bits
    int idx = gid - 2624;
    int j = idx / 32, k = idx % 32;
    int w = k & 15, hi = k >> 4;
    u64 b = 0;
    for (int l = 0; l < 64; ++l) {
      int i = (hi * 64 + l) * 16 + w;
      if (P.p[25][j * 2048 + i] > 0.0f) b |= (1ull << l);
    }
    g_wfcb[j * 32 + k] = b;
  }
}

// ----------------------- fused binary network ------------------------------
__global__ __launch_bounds__(256) void fused_kernel(const float* __restrict__ x,
                                                    float* __restrict__ out) {
  const int n = blockIdx.x;
  const int tid = threadIdx.x;
  const int lane = tid & 63;
  const int wave = tid >> 6;
  const float* xi = x + (size_t)n * 768;

  __shared__ u64 xb[12];       // input sign bits, 6 rows x 128 bits
  __shared__ u64 xp[18];       // padded (<<4) rows, 3 u64 per row
  __shared__ u32 c1s[384];     // conv1 out (h*64+w'), bit = channel
  __shared__ u32 p1s[194];     // pooled (h*32+w), +2 pad for rotation
  __shared__ u64 c2s[194];     // conv2 out (h*32+w), +2 pad
  __shared__ u64 c3s[384];     // conv3 out (h*32+w)*2+half
  __shared__ u64 p3s[192];     // pooled (h*16+w)*2+half
  __shared__ u64 c4s[32];      // conv4 out w*2+half
  __shared__ int fcacc[6];

  if (tid < 6) fcacc[tid] = 0;
  if (tid >= 192 && tid < 196) { p1s[192 + (tid - 192) & 1 ? 193 : 192] = 0; }
  // (simpler: explicitly zero pads below)
  if (tid == 6) { p1s[192] = 0; p1s[193] = 0; }
  if (tid == 7) { c2s[192] = 0; c2s[193] = 0; }

  // ---- stage A: binarize input ----
  #pragma unroll
  for (int base = 0; base < 768; base += 256) {
    int idx = base + tid;                    // lane == bit position in word
    float v = xi[idx];
    u64 m = __ballot(v > 0.0f);
    if (lane == 0) xb[idx >> 6] = m;
  }
  __syncthreads();

  // build padded rows: row h -> 3 u64, pre-shifted by 4 (pad bits = 0)
  if (tid < 6) {
    u64 r0 = xb[2 * tid], r1 = xb[2 * tid + 1];
    xp[tid * 3 + 0] = r0 << 4;
    xp[tid * 3 + 1] = (r0 >> 60) | (r1 << 4);
    xp[tid * 3 + 2] = r1 >> 60;
  }
  __syncthreads();

  // ---- conv1 (1->32, k=9, s=2, pad 4) + sign ----
  {
    const int c = lane & 31;
    const int sub = lane >> 5;
    const u32 wv = g_w1b[c];
    const int c9 = 9 - g_s1[c];
    const u64 fl1 = g_flip1;
    #pragma unroll 4
    for (int it = 0; it < 48; ++it) {
      int p = it * 8 + wave * 2 + sub;       // 0..383 : h*64 + w'
      int h = p >> 6, wp = p & 63;
      int q = wp * 2;                        // padded bit offset of window
      int widx = wp >> 5, sh = q & 63;
      u64 lo = xp[h * 3 + widx];
      u64 hi = xp[h * 3 + widx + 1];
      u32 win = (u32)((lo >> sh) | ((hi << 1) << (63 - sh)));
      int L = 4 - q;  L = L > 0 ? L : 0;     // invalid left taps
      int R = q - 123; R = R > 0 ? R : 0;    // invalid right taps
      u32 vm = (0x1FFu << L) & (0x1FFu >> R);
      int P = __popc((win ^ wv) & vm);
      int pred = (2 * P) <= (c9 - L - R);
      u64 mm = __ballot(pred) ^ fl1;
      if (lane == 0) { c1s[p] = (u32)mm; c1s[p + 1] = (u32)(mm >> 32); }
    }
  }
  __syncthreads();

  // ---- maxpool (1,2): sign-max == OR ----
  if (tid < 192) {
    int h = tid >> 5, w = tid & 31;
    p1s[tid] = c1s[h * 64 + 2 * w] | c1s[h * 64 + 2 * w + 1];
  }
  __syncthreads();

  // ---- conv2 (32->64, k=3, pad 1) + sign ----
  {
    const int c = lane;
    const u32 w1c = g_w2b[c * 3 + 1];
    const u64 pk = (u64)g_w2b[c * 3 + 0] | ((u64)g_w2b[c * 3 + 2] << 32);
    const int D96 = 96 - g_s2[c], D64 = 64 - g_s2[c];
    const u64 fl2 = g_flip2;
    const int p0 = wave * 48;
    u32 a0 = (p0 > 0) ? p1s[p0 - 1] : 0u;
    u32 a1 = p1s[p0];
    u32 a2 = p1s[p0 + 1];
    #pragma unroll 4
    for (int it = 0; it < 48; ++it) {
      int p = p0 + it, w = p & 31;
      int P = __popc(a1 ^ w1c);
      int pred;
      if (w == 0) {
        P += __popcll((((u64)a2) << 32) ^ (pk & 0xFFFFFFFF00000000ULL));
        pred = 2 * P <= D64;
      } else if (w == 31) {
        P += __popcll(((u64)a0) ^ (pk & 0xFFFFFFFFULL));
        pred = 2 * P <= D64;
      } else {
        P += __popcll(((((u64)a2) << 32) | a0) ^ pk);
        pred = 2 * P <= D96;
      }
      u64 mm = __ballot(pred) ^ fl2;
      if (lane == 0) c2s[p] = mm;
      a0 = a1; a1 = a2; a2 = p1s[p + 2];
    }
  }
  __syncthreads();

  // ---- conv3 (64->128, k=3, pad 1) + sign ----
  {
    const u64 wl0 = g_w3b[lane * 3 + 0], wl1 = g_w3b[lane * 3 + 1], wl2 = g_w3b[lane * 3 + 2];
    const u64 wh0 = g_w3b[(64 + lane) * 3 + 0], wh1 = g_w3b[(64 + lane) * 3 + 1], wh2 = g_w3b[(64 + lane) * 3 + 2];
    const int Da192 = 192 - g_s3[lane], Da128 = 128 - g_s3[lane];
    const int Db192 = 192 - g_s3[64 + lane], Db128 = 128 - g_s3[64 + lane];
    const u64 fl3a = g_flip3[0], fl3b = g_flip3[1];
    const int p0 = wave * 48;
    u64 cl = (p0 > 0) ? c2s[p0 - 1] : 0ull;
    u64 cc = c2s[p0];
    u64 cr = c2s[p0 + 1];
    #pragma unroll 2
    for (int it = 0; it < 48; ++it) {
      int p = p0 + it, w = p & 31;
      int P0 = __popcll(cc ^ wl1);
      int P1 = __popcll(cc ^ wh1);
      int pred0, pred1;
      if (w == 0) {
        P0 += __popcll(cr ^ wl2); P1 += __popcll(cr ^ wh2);
        pred0 = 2 * P0 <= Da128; pred1 = 2 * P1 <= Db128;
      } else if (w == 31) {
        P0 += __popcll(cl ^ wl0); P1 += __popcll(cl ^ wh0);
        pred0 = 2 * P0 <= Da128; pred1 = 2 * P1 <= Db128;
      } else {
        P0 += __popcll(cl ^ wl0) + __popcll(cr ^ wl2);
        P1 += __popcll(cl ^ wh0) + __popcll(cr ^ wh2);
        pred0 = 2 * P0 <= Da192; pred1 = 2 * P1 <= Db192;
      }
      u64 m0 = __ballot(pred0) ^ fl3a;
      u64 m1 = __ballot(pred1) ^ fl3b;
      if (lane == 0) { c3s[2 * p] = m0; c3s[2 * p + 1] = m1; }
      cl = cc; cc = cr; cr = c2s[p + 2];
    }
  }
  __syncthreads();

  // ---- maxpool (1,2) ----
  if (tid < 192) {
    int h = tid / 32, r = tid % 32, w = r >> 1, hf = r & 1;
    p3s[(h * 16 + w) * 2 + hf] =
        c3s[(h * 32 + 2 * w) * 2 + hf] | c3s[(h * 32 + 2 * w + 1) * 2 + hf];
  }
  __syncthreads();

  // ---- conv4 (128->128, k=(6,1)) + sign ----
  {
    const int Da = 768 - g_s4[lane], Db = 768 - g_s4[64 + lane];
    const u64 fl4a = g_flip4[0], fl4b = g_flip4[1];
    #pragma unroll
    for (int it = 0; it < 4; ++it) {
      int w = it * 4 + wave;
      int acc0 = 0, acc1 = 0;
      #pragma unroll
      for (int h = 0; h < 6; ++h) {
        u64 aL = p3s[(h * 16 + w) * 2];
        u64 aH = p3s[(h * 16 + w) * 2 + 1];
        acc0 += __popcll(aL ^ g_w4b[(lane * 6 + h) * 2]) +
                __popcll(aH ^ g_w4b[(lane * 6 + h) * 2 + 1]);
        acc1 += __popcll(aL ^ g_w4b[((64 + lane) * 6 + h) * 2]) +
                __popcll(aH ^ g_w4b[((64 + lane) * 6 + h) * 2 + 1]);
      }
      int pred0 = 2 * acc0 <= Da;
      int pred1 = 2 * acc1 <= Db;
      u64 m0 = __ballot(pred0) ^ fl4a;
      u64 m1 = __ballot(pred1) ^ fl4b;
      if (lane == 0) { c4s[w * 2] = m0; c4s[w * 2 + 1] = m1; }
    }
  }
  __syncthreads();

  // ---- FC: sign(h) . sign(wfc)^T + bfc ----
  if (tid < 192) {
    int j = tid >> 5, k = tid & 31;
    int w = k & 15, hf = k >> 4;
    int pc = __popcll(c4s[w * 2 + hf] ^ g_wfcb[j * 32 + k]);
    atomicAdd(&fcacc[j], pc);
  }
  __syncthreads();
  if (tid < 6) {
    out[(size_t)n * 6 + tid] =
        __fadd_rn((float)(2048 - 2 * fcacc[tid]), g_bfc[tid]);
  }
}

// ------------------------------ launch --------------------------------------
extern "C" void kernel_launch(void* const* d_in, const int* in_sizes, int n_in,
                              void* d_out, int out_size, void* d_ws, size_t ws_size,
                              hipStream_t stream) {
  (void)d_ws; (void)ws_size; (void)n_in;
  Ptrs P;
  for (int i = 0; i < 27; ++i) P.p[i] = (const float*)d_in[i];

  hipLaunchKernelGGL(prepack_kernel, dim3(11), dim3(256), 0, stream, P);

  const float* x = (const float*)d_in[0];
  float* out = (float*)d_out;
  int B = in_sizes[0] / 768;                 // 4096
  hipLaunchKernelGGL(fused_kernel, dim3(B), dim3(256), 0, stream, x, out);
}

// Round 3
// 109.128 us; speedup vs baseline: 2.1910x; 1.1868x over previous
//
#include <hip/hip_runtime.h>

typedef unsigned long long u64;
typedef unsigned int u32;

// ---------------- packed weights / integer thresholds (device globals) ------
__device__ u32 g_w1b[32];                 // 9 taps in low bits
__device__ u32 g_w2b[64 * 3];             // [c][k], bit = cin (0..31)
__device__ u64 g_w3b[128 * 3];            // [c][k], bit = cin (0..63)
__device__ u64 g_w4b[128 * 6 * 2];        // [c][h][hi], bit l = cin hi*64+l
__device__ u64 g_wfcb[6 * 32];            // [j][k]: w=k%16, hi=k/16, bit l -> i=(hi*64+l)*16+w
__device__ float g_bfc[6];

__device__ int g_s1[32], g_s2[64], g_s3[128], g_s4[128];   // integer S-thresholds
__device__ u64 g_flip1, g_flip2, g_flip3[2], g_flip4[2];   // per-layer flip masks

struct Ptrs { const float* p[27]; };

// exact f32 op order of the np reference: y = ((S + b) * inv) + t, no FMA
__device__ __forceinline__ int predS(int S, float b, float inv, float t) {
  float hv = __fadd_rn((float)S, b);
  float y = __fadd_rn(__fmul_rn(hv, inv), t);
  return y > 0.0f;
}

__device__ __forceinline__ void bn_fold(float b, float g, float be, float m, float v,
                                        float* ob, float* oinv, float* ot) {
  double iv = (double)g * (1.0 / sqrt((double)v + 1e-5));
  float invf = (float)iv;
  *ob = b;
  *oinv = invf;
  *ot = __fadd_rn(be, -__fmul_rn(m, invf));
}

// pred(S) == (S >= smin) XOR flip, exactly, for all integer S in range.
__device__ __forceinline__ void find_thr(float bias, float g, float be, float m, float v,
                                         int* smin, int* flip) {
  float b, inv, t;
  bn_fold(bias, g, be, m, v, &b, &inv, &t);
  int pl = predS(-2048, b, inv, t), ph = predS(2048, b, inv, t);
  if (pl && ph) { *smin = -4096; *flip = 0; }
  else if (!pl && !ph) { *smin = 4096; *flip = 0; }
  else if (!pl && ph) {
    int lo = -2048, hi = 2048;
    while (hi - lo > 1) { int md = (lo + hi) >> 1; if (predS(md, b, inv, t)) hi = md; else lo = md; }
    *smin = hi; *flip = 0;
  } else {
    int lo = -2048, hi = 2048;
    while (hi - lo > 1) { int md = (lo + hi) >> 1; if (predS(md, b, inv, t)) lo = md; else hi = md; }
    *smin = lo + 1; *flip = 1;
  }
}

// -------------------------- weight prepack ---------------------------------
__global__ __launch_bounds__(256) void prepack_kernel(Ptrs P) {
  int tid = threadIdx.x;
  int gid = blockIdx.x * 256 + tid;
  if (gid < 32) {
    int c = gid, smin, flip;
    find_thr(P.p[2][c], P.p[3][c], P.p[4][c], P.p[5][c], P.p[6][c], &smin, &flip);
    g_s1[c] = smin;
    u64 fl = __ballot(flip != 0);
    if (c == 0) g_flip1 = (fl & 0xFFFFFFFFULL) | (fl << 32);
  } else if (gid >= 64 && gid < 128) {
    int c = gid - 64, smin, flip;
    find_thr(P.p[8][c], P.p[9][c], P.p[10][c], P.p[11][c], P.p[12][c], &smin, &flip);
    g_s2[c] = smin;
    u64 fl = __ballot(flip != 0);
    if (c == 0) g_flip2 = fl;
  } else if (gid >= 128 && gid < 256) {
    int c = gid - 128, smin, flip;
    find_thr(P.p[14][c], P.p[15][c], P.p[16][c], P.p[17][c], P.p[18][c], &smin, &flip);
    g_s3[c] = smin;
    u64 fl = __ballot(flip != 0);
    if ((c & 63) == 0) g_flip3[c >> 6] = fl;
  } else if (gid >= 256 && gid < 384) {
    int c = gid - 256, smin, flip;
    find_thr(P.p[20][c], P.p[21][c], P.p[22][c], P.p[23][c], P.p[24][c], &smin, &flip);
    g_s4[c] = smin;
    u64 fl = __ballot(flip != 0);
    if ((c & 63) == 0) g_flip4[c >> 6] = fl;
  } else if (gid >= 384 && gid < 416) {
    int c = gid - 384;
    u32 b = 0;
    for (int k = 0; k < 9; ++k)
      if (P.p[1][c * 9 + k] > 0.0f) b |= (1u << k);
    g_w1b[c] = b;
  } else if (gid >= 416 && gid < 422) {
    g_bfc[gid - 416] = P.p[26][gid - 416];
  } else if (gid >= 512 && gid < 704) {
    int idx = gid - 512;
    int c = idx / 3, k = idx % 3;
    u32 b = 0;
    for (int cin = 0; cin < 32; ++cin)
      if (P.p[7][(c * 32 + cin) * 3 + k] > 0.0f) b |= (1u << cin);
    g_w2b[c * 3 + k] = b;
  } else if (gid >= 704 && gid < 1088) {
    int idx = gid - 704;
    int c = idx / 3, k = idx % 3;
    u64 b = 0;
    for (int cin = 0; cin < 64; ++cin)
      if (P.p[13][(c * 64 + cin) * 3 + k] > 0.0f) b |= (1ull << cin);
    g_w3b[c * 3 + k] = b;
  } else if (gid >= 1088 && gid < 2624) {
    int idx = gid - 1088;
    int c = idx / 12, r = idx % 12, h = r >> 1, hi = r & 1;
    u64 b = 0;
    for (int l = 0; l < 64; ++l) {
      int cin = hi * 64 + l;
      if (P.p[19][(c * 128 + cin) * 6 + h] > 0.0f) b |= (1ull << l);
    }
    g_w4b[(c * 6 + h) * 2 + hi] = b;
  } else if (gid >= 2624 && gid < 2816) {
    int idx = gid - 2624;
    int j = idx / 32, k = idx % 32;
    int w = k & 15, hi = k >> 4;
    u64 b = 0;
    for (int l = 0; l < 64; ++l) {
      int i = (hi * 64 + l) * 16 + w;
      if (P.p[25][j * 2048 + i] > 0.0f) b |= (1ull << l);
    }
    g_wfcb[j * 32 + k] = b;
  }
}

// ----------------------- fused binary network ------------------------------
// ONE WAVE PER IMAGE. 4 images per 256-thread block, disjoint LDS regions,
// zero __syncthreads (in-order wave + compiler waitcnt give LDS ordering).
struct WaveMem {
  u64 xp[18];      // padded (<<4) input rows, 3 u64 per row
  u64 c2s[192];    // conv2 out (h*32+w), bit = channel
  u64 p3s[192];    // conv3+pool out (h*16+w)*2+half
  u64 c4s[32];     // conv4 out w*2+half
  u32 p1s[196];    // conv1+pool out (h*32+w), +pads (192..193 zero)
};

__global__ __launch_bounds__(256) void fused_kernel(const float* __restrict__ x,
                                                    float* __restrict__ out, int B) {
  const int tid = threadIdx.x;
  const int lane = tid & 63;
  const int wave = tid >> 6;
  const int n = blockIdx.x * 4 + wave;
  if (n >= B) return;                      // wave-uniform
  const float* xi = x + (size_t)n * 768;

  __shared__ WaveMem wm[4];
  WaveMem& W = wm[wave];

  // ---- stage A: binarize input, build padded rows directly ----
  #pragma unroll
  for (int h = 0; h < 6; ++h) {
    float v0 = xi[h * 128 + lane];
    float v1 = xi[h * 128 + 64 + lane];
    u64 m0 = __ballot(v0 > 0.0f);
    u64 m1 = __ballot(v1 > 0.0f);
    if (lane == 0) {
      W.xp[h * 3 + 0] = m0 << 4;
      W.xp[h * 3 + 1] = (m0 >> 60) | (m1 << 4);
      W.xp[h * 3 + 2] = m1 >> 60;
    }
  }
  if (lane < 2) W.p1s[192 + lane] = 0;

  // ---- conv1 (1->32, k=9, s=2, pad 4) + sign + pool, fused ----
  {
    const int c = lane & 31;
    const int sub = lane >> 5;
    const u32 wv = g_w1b[c];
    const int s = g_s1[c];
    const int f1 = (int)((g_flip1 >> lane) & 1);
    // thresholds with edge-clip + zero-pad correction folded in
    const int D0i = 9 - s;
    const int D0a = 5 - s + 2 * __popc(wv & 0x00F);   // pw==0, win0: taps k<4 invalid
    const int D0b = 8 - s + 2 * __popc(wv & 0x100);   // pw==31, win0: tap k=8 invalid
    const int D1i = 9 - s;
    const int D1a = 7 - s + 2 * __popc(wv & 0x003);   // pw==0, win1: taps k<2 invalid
    const int D1b = 6 - s + 2 * __popc(wv & 0x1C0);   // pw==31, win1: taps k>=6 invalid
    #pragma unroll 4
    for (int it = 0; it < 96; ++it) {
      int pp = 2 * it + sub;               // pooled position, uniform per half-wave
      int pw = pp & 31, h = pp >> 5;
      int widx = pw >> 4;
      int sh = (pw << 2) & 63;
      u64 lo = W.xp[h * 3 + widx];
      u64 hi = W.xp[h * 3 + widx + 1];
      u32 win = (u32)((lo >> sh) | ((hi << 1) << (63 - sh)));  // 11 bits live
      int e0 = (pw == 0), e31 = (pw == 31);
      int D0 = e0 ? D0a : (e31 ? D0b : D0i);
      int D1 = e0 ? D1a : (e31 ? D1b : D1i);
      int P0 = __popc((win ^ wv) & 0x1FF);
      int P1 = __popc(((win >> 2) ^ wv) & 0x1FF);
      int pred = ((2 * P0 <= D0) ^ f1) | ((2 * P1 <= D1) ^ f1);
      u64 mm = __ballot(pred);
      if (lane == 0) { W.p1s[pp] = (u32)mm; W.p1s[pp + 1] = (u32)(mm >> 32); }
    }
  }

  // ---- conv2 (32->64, k=3, pad 1) + sign ----
  {
    const u32 w2m = g_w2b[lane * 3 + 1];
    const u64 pk = (u64)g_w2b[lane * 3 + 0] | ((u64)g_w2b[lane * 3 + 2] << 32);
    const u64 pkL = pk & 0xFFFFFFFFULL, pkH = pk & 0xFFFFFFFF00000000ULL;
    const int s2 = g_s2[lane];
    const int D96 = 96 - s2, D64 = 64 - s2;
    const u64 fl2 = g_flip2;
    u32 a0 = 0, a1 = W.p1s[0], a2 = W.p1s[1];
    #pragma unroll 4
    for (int it = 0; it < 192; ++it) {     // position uniform across wave
      int w = it & 31;
      int P = __popc(a1 ^ w2m);
      int pred;
      if (w == 0) {
        P += __popcll((((u64)a2) << 32) ^ pkH);
        pred = 2 * P <= D64;
      } else if (w == 31) {
        P += __popcll(((u64)a0) ^ pkL);
        pred = 2 * P <= D64;
      } else {
        P += __popcll(((((u64)a2) << 32) | a0) ^ pk);
        pred = 2 * P <= D96;
      }
      u64 mm = __ballot(pred) ^ fl2;
      if (lane == 0) W.c2s[it] = mm;
      a0 = a1; a1 = a2; a2 = W.p1s[it + 2];
    }
  }

  // ---- conv3 (64->128, k=3, pad 1) + sign + pool, fused ----
  {
    const u64 wl0 = g_w3b[lane * 3 + 0], wl1 = g_w3b[lane * 3 + 1], wl2 = g_w3b[lane * 3 + 2];
    const u64 wh0 = g_w3b[(64 + lane) * 3 + 0], wh1 = g_w3b[(64 + lane) * 3 + 1], wh2 = g_w3b[(64 + lane) * 3 + 2];
    const int sa = g_s3[lane], sb = g_s3[64 + lane];
    const int Da192 = 192 - sa, Da128 = 128 - sa;
    const int Db192 = 192 - sb, Db128 = 128 - sb;
    const int f3a = (int)((g_flip3[0] >> lane) & 1);
    const int f3b = (int)((g_flip3[1] >> lane) & 1);
    #pragma unroll 2
    for (int it = 0; it < 96; ++it) {      // pooled position, uniform across wave
      int pw = it & 15;
      int base = (it >> 4) * 32 + 2 * pw;
      u64 Bm = W.c2s[base], Cm = W.c2s[base + 1];
      int predA, predB;
      if (pw == 0) {
        u64 Dm = W.c2s[base + 2];
        int P0a = __popcll(Bm ^ wl1) + __popcll(Cm ^ wl2);
        int P1a = __popcll(Bm ^ wl0) + __popcll(Cm ^ wl1) + __popcll(Dm ^ wl2);
        int P0b = __popcll(Bm ^ wh1) + __popcll(Cm ^ wh2);
        int P1b = __popcll(Bm ^ wh0) + __popcll(Cm ^ wh1) + __popcll(Dm ^ wh2);
        predA = ((2 * P0a <= Da128) ^ f3a) | ((2 * P1a <= Da192) ^ f3a);
        predB = ((2 * P0b <= Db128) ^ f3b) | ((2 * P1b <= Db192) ^ f3b);
      } else if (pw == 15) {
        u64 Am = W.c2s[base - 1];
        int P0a = __popcll(Am ^ wl0) + __popcll(Bm ^ wl1) + __popcll(Cm ^ wl2);
        int P1a = __popcll(Bm ^ wl0) + __popcll(Cm ^ wl1);
        int P0b = __popcll(Am ^ wh0) + __popcll(Bm ^ wh1) + __popcll(Cm ^ wh2);
        int P1b = __popcll(Bm ^ wh0) + __popcll(Cm ^ wh1);
        predA = ((2 * P0a <= Da192) ^ f3a) | ((2 * P1a <= Da128) ^ f3a);
        predB = ((2 * P0b <= Db192) ^ f3b) | ((2 * P1b <= Db128) ^ f3b);
      } else {
        u64 Am = W.c2s[base - 1], Dm = W.c2s[base + 2];
        int P0a = __popcll(Am ^ wl0) + __popcll(Bm ^ wl1) + __popcll(Cm ^ wl2);
        int P1a = __popcll(Bm ^ wl0) + __popcll(Cm ^ wl1) + __popcll(Dm ^ wl2);
        int P0b = __popcll(Am ^ wh0) + __popcll(Bm ^ wh1) + __popcll(Cm ^ wh2);
        int P1b = __popcll(Bm ^ wh0) + __popcll(Cm ^ wh1) + __popcll(Dm ^ wh2);
        predA = ((2 * P0a <= Da192) ^ f3a) | ((2 * P1a <= Da192) ^ f3a);
        predB = ((2 * P0b <= Db192) ^ f3b) | ((2 * P1b <= Db192) ^ f3b);
      }
      u64 m0 = __ballot(predA);
      u64 m1 = __ballot(predB);
      if (lane == 0) { W.p3s[2 * it] = m0; W.p3s[2 * it + 1] = m1; }
    }
  }

  // ---- conv4 (128->128, k=(6,1)) + sign ----
  {
    u64 wA[12], wB[12];                    // hoisted weights: [h*2+hi]
    #pragma unroll
    for (int h = 0; h < 6; ++h) {
      wA[h * 2 + 0] = g_w4b[(lane * 6 + h) * 2 + 0];
      wA[h * 2 + 1] = g_w4b[(lane * 6 + h) * 2 + 1];
      wB[h * 2 + 0] = g_w4b[((64 + lane) * 6 + h) * 2 + 0];
      wB[h * 2 + 1] = g_w4b[((64 + lane) * 6 + h) * 2 + 1];
    }
    const int Da = 768 - g_s4[lane], Db = 768 - g_s4[64 + lane];
    const u64 fl4a = g_flip4[0], fl4b = g_flip4[1];
    for (int w = 0; w < 16; ++w) {         // uniform across wave
      int accA = 0, accB = 0;
      #pragma unroll
      for (int h = 0; h < 6; ++h) {
        u64 aL = W.p3s[(h * 16 + w) * 2];
        u64 aH = W.p3s[(h * 16 + w) * 2 + 1];
        accA += __popcll(aL ^ wA[h * 2]) + __popcll(aH ^ wA[h * 2 + 1]);
        accB += __popcll(aL ^ wB[h * 2]) + __popcll(aH ^ wB[h * 2 + 1]);
      }
      u64 m0 = __ballot(2 * accA <= Da) ^ fl4a;
      u64 m1 = __ballot(2 * accB <= Db) ^ fl4b;
      if (lane == 0) { W.c4s[2 * w] = m0; W.c4s[2 * w + 1] = m1; }
    }
  }

  // ---- FC: sign(h) . sign(wfc)^T + bfc  (shuffle reduce, no atomics) ----
  {
    const int k = lane & 31, half = lane >> 5;
    u64 hw = W.c4s[(k & 15) * 2 + (k >> 4)];
    #pragma unroll
    for (int it = 0; it < 3; ++it) {
      int j = 2 * it + half;
      int pc = __popcll(hw ^ g_wfcb[j * 32 + k]);
      pc += __shfl_xor(pc, 16);
      pc += __shfl_xor(pc, 8);
      pc += __shfl_xor(pc, 4);
      pc += __shfl_xor(pc, 2);
      pc += __shfl_xor(pc, 1);
      if (k == 0)
        out[(size_t)n * 6 + j] = __fadd_rn((float)(2048 - 2 * pc), g_bfc[j]);
    }
  }
}

// ------------------------------ launch --------------------------------------
extern "C" void kernel_launch(void* const* d_in, const int* in_sizes, int n_in,
                              void* d_out, int out_size, void* d_ws, size_t ws_size,
                              hipStream_t stream) {
  (void)d_ws; (void)ws_size; (void)n_in;
  Ptrs P;
  for (int i = 0; i < 27; ++i) P.p[i] = (const float*)d_in[i];

  hipLaunchKernelGGL(prepack_kernel, dim3(11), dim3(256), 0, stream, P);

  const float* x = (const float*)d_in[0];
  float* out = (float*)d_out;
  int B = in_sizes[0] / 768;                 // 4096
  hipLaunchKernelGGL(fused_kernel, dim3((B + 3) / 4), dim3(256), 0, stream, x, out, B);
}

// Round 4
// 106.488 us; speedup vs baseline: 2.2453x; 1.0248x over previous
//
#include <hip/hip_runtime.h>

typedef unsigned long long u64;
typedef unsigned int u32;

// ---------------- packed weights / integer thresholds (device globals) ------
__device__ u32 g_w1b[32];                 // 9 taps in low bits
__device__ u32 g_w2b[64 * 3];             // [c][k], bit = cin (0..31)
__device__ u64 g_w3b[128 * 3];            // [c][k], bit = cin (0..63)
__device__ u64 g_w4b[128 * 6 * 2];        // [c][h][hi], bit l = cin hi*64+l
__device__ u64 g_wfcb[6 * 32];            // [j][k]: w=k%16, hi=k/16, bit l -> i=(hi*64+l)*16+w
__device__ float g_bfc[6];

__device__ int g_s1[32], g_s2[64], g_s3[128], g_s4[128];   // integer S-thresholds
__device__ u64 g_flip1, g_flip2, g_flip3[2], g_flip4[2];   // per-layer flip masks

struct Ptrs { const float* p[27]; };

// exact f32 op order of the np reference: y = ((S + b) * inv) + t, no FMA
__device__ __forceinline__ int predS(int S, float b, float inv, float t) {
  float hv = __fadd_rn((float)S, b);
  float y = __fadd_rn(__fmul_rn(hv, inv), t);
  return y > 0.0f;
}

__device__ __forceinline__ void bn_fold(float b, float g, float be, float m, float v,
                                        float* ob, float* oinv, float* ot) {
  double iv = (double)g * (1.0 / sqrt((double)v + 1e-5));
  float invf = (float)iv;
  *ob = b;
  *oinv = invf;
  *ot = __fadd_rn(be, -__fmul_rn(m, invf));
}

// pred(S) == (S >= smin) XOR flip, exactly, for all integer S in range.
__device__ __forceinline__ void find_thr(float bias, float g, float be, float m, float v,
                                         int* smin, int* flip) {
  float b, inv, t;
  bn_fold(bias, g, be, m, v, &b, &inv, &t);
  int pl = predS(-2048, b, inv, t), ph = predS(2048, b, inv, t);
  if (pl && ph) { *smin = -4096; *flip = 0; }
  else if (!pl && !ph) { *smin = 4096; *flip = 0; }
  else if (!pl && ph) {
    int lo = -2048, hi = 2048;
    while (hi - lo > 1) { int md = (lo + hi) >> 1; if (predS(md, b, inv, t)) hi = md; else lo = md; }
    *smin = hi; *flip = 0;
  } else {
    int lo = -2048, hi = 2048;
    while (hi - lo > 1) { int md = (lo + hi) >> 1; if (predS(md, b, inv, t)) lo = md; else hi = md; }
    *smin = lo + 1; *flip = 1;
  }
}

// -------------------------- weight prepack ---------------------------------
__global__ __launch_bounds__(256) void prepack_kernel(Ptrs P) {
  int tid = threadIdx.x;
  int gid = blockIdx.x * 256 + tid;
  if (gid < 32) {
    int c = gid, smin, flip;
    find_thr(P.p[2][c], P.p[3][c], P.p[4][c], P.p[5][c], P.p[6][c], &smin, &flip);
    g_s1[c] = smin;
    u64 fl = __ballot(flip != 0);
    if (c == 0) g_flip1 = (fl & 0xFFFFFFFFULL) | (fl << 32);
  } else if (gid >= 64 && gid < 128) {
    int c = gid - 64, smin, flip;
    find_thr(P.p[8][c], P.p[9][c], P.p[10][c], P.p[11][c], P.p[12][c], &smin, &flip);
    g_s2[c] = smin;
    u64 fl = __ballot(flip != 0);
    if (c == 0) g_flip2 = fl;
  } else if (gid >= 128 && gid < 256) {
    int c = gid - 128, smin, flip;
    find_thr(P.p[14][c], P.p[15][c], P.p[16][c], P.p[17][c], P.p[18][c], &smin, &flip);
    g_s3[c] = smin;
    u64 fl = __ballot(flip != 0);
    if ((c & 63) == 0) g_flip3[c >> 6] = fl;
  } else if (gid >= 256 && gid < 384) {
    int c = gid - 256, smin, flip;
    find_thr(P.p[20][c], P.p[21][c], P.p[22][c], P.p[23][c], P.p[24][c], &smin, &flip);
    g_s4[c] = smin;
    u64 fl = __ballot(flip != 0);
    if ((c & 63) == 0) g_flip4[c >> 6] = fl;
  } else if (gid >= 384 && gid < 416) {
    int c = gid - 384;
    u32 b = 0;
    for (int k = 0; k < 9; ++k)
      if (P.p[1][c * 9 + k] > 0.0f) b |= (1u << k);
    g_w1b[c] = b;
  } else if (gid >= 416 && gid < 422) {
    g_bfc[gid - 416] = P.p[26][gid - 416];
  } else if (gid >= 512 && gid < 704) {
    int idx = gid - 512;
    int c = idx / 3, k = idx % 3;
    u32 b = 0;
    for (int cin = 0; cin < 32; ++cin)
      if (P.p[7][(c * 32 + cin) * 3 + k] > 0.0f) b |= (1u << cin);
    g_w2b[c * 3 + k] = b;
  } else if (gid >= 704 && gid < 1088) {
    int idx = gid - 704;
    int c = idx / 3, k = idx % 3;
    u64 b = 0;
    for (int cin = 0; cin < 64; ++cin)
      if (P.p[13][(c * 64 + cin) * 3 + k] > 0.0f) b |= (1ull << cin);
    g_w3b[c * 3 + k] = b;
  } else if (gid >= 1088 && gid < 2624) {
    int idx = gid - 1088;
    int c = idx / 12, r = idx % 12, h = r >> 1, hi = r & 1;
    u64 b = 0;
    for (int l = 0; l < 64; ++l) {
      int cin = hi * 64 + l;
      if (P.p[19][(c * 128 + cin) * 6 + h] > 0.0f) b |= (1ull << l);
    }
    g_w4b[(c * 6 + h) * 2 + hi] = b;
  } else if (gid >= 2624 && gid < 2816) {
    int idx = gid - 2624;
    int j = idx / 32, k = idx % 32;
    int w = k & 15, hi = k >> 4;
    u64 b = 0;
    for (int l = 0; l < 64; ++l) {
      int i = (hi * 64 + l) * 16 + w;
      if (P.p[25][j * 2048 + i] > 0.0f) b |= (1ull << l);
    }
    g_wfcb[j * 32 + k] = b;
  }
}

// ----------------------- fused binary network ------------------------------
// TWO WAVES PER IMAGE (rows 0-2 / 3-5; conv1..conv3 have kernel height 1 so
// rows are independent). 2 images per 256-thread block. Barriers only before
// conv4 (k=(6,1) mixes rows) and before FC.
struct WaveMem {
  u64 xp[18];      // padded (<<4) input rows, 3 u64 per row
  u64 c2s[192];    // conv2 out (h*32+w), bit = channel
  u64 p3s[192];    // conv3+pool out (h*16+w)*2+half
  u64 c4s[32];     // conv4 out w*2+chanhalf
  u32 p1s[194];    // conv1+pool out (h*32+w), +2 overrun slots (values unused)
};

__global__ __launch_bounds__(256) void fused_kernel(const float* __restrict__ x,
                                                    float* __restrict__ out, int B) {
  const int tid = threadIdx.x;
  const int lane = tid & 63;
  const int wave = tid >> 6;         // 0..3
  const int img = wave >> 1;         // 0..1 within block
  const int half = wave & 1;         // row-half of the image
  const int n = blockIdx.x * 2 + img;
  const bool active = (n < B);

  __shared__ WaveMem wm[2];
  WaveMem& W = wm[img];
  const float* xi = x + (size_t)n * 768;

  if (active) {
    // ---- stage A: binarize this wave's 3 rows into padded form ----
    #pragma unroll
    for (int hl = 0; hl < 3; ++hl) {
      int h = half * 3 + hl;
      float v0 = xi[h * 128 + lane];
      float v1 = xi[h * 128 + 64 + lane];
      u64 m0 = __ballot(v0 > 0.0f);
      u64 m1 = __ballot(v1 > 0.0f);
      if (lane == 0) {
        W.xp[h * 3 + 0] = m0 << 4;
        W.xp[h * 3 + 1] = (m0 >> 60) | (m1 << 4);
        W.xp[h * 3 + 2] = m1 >> 60;
      }
    }

    // ---- conv1 (1->32, k=9, s=2, pad 4) + sign + pool ----
    {
      const int c = lane & 31;
      const int sub = lane >> 5;
      const u32 wv = g_w1b[c];
      const int s = g_s1[c];
      const int f1 = (int)((g_flip1 >> lane) & 1);
      const int D0i = 9 - s;
      const int D0a = 5 - s + 2 * __popc(wv & 0x00F);   // pw==0, win0
      const int D0b = 8 - s + 2 * __popc(wv & 0x100);   // pw==31, win0
      const int D1i = 9 - s;
      const int D1a = 7 - s + 2 * __popc(wv & 0x003);   // pw==0, win1
      const int D1b = 6 - s + 2 * __popc(wv & 0x1C0);   // pw==31, win1
      #pragma unroll 4
      for (int it = 0; it < 48; ++it) {
        int ppl = 2 * it + sub;            // local pooled pos 0..95
        int pw = ppl & 31, hl = ppl >> 5;
        int h = half * 3 + hl;
        int widx = pw >> 4;
        int sh = (pw << 2) & 63;
        u64 lo = W.xp[h * 3 + widx];
        u64 hi = W.xp[h * 3 + widx + 1];
        u32 win = (u32)((lo >> sh) | ((hi << 1) << (63 - sh)));  // 11 bits live
        int e0 = (pw == 0), e31 = (pw == 31);
        int D0 = e0 ? D0a : (e31 ? D0b : D0i);
        int D1 = e0 ? D1a : (e31 ? D1b : D1i);
        int P0 = __popc((win ^ wv) & 0x1FF);
        int P1 = __popc(((win >> 2) ^ wv) & 0x1FF);
        int pred = ((2 * P0 <= D0) ^ f1) | ((2 * P1 <= D1) ^ f1);
        u64 mm = __ballot(pred);
        int ppg = half * 96 + 2 * it;
        if (lane == 0) { W.p1s[ppg] = (u32)mm; W.p1s[ppg + 1] = (u32)(mm >> 32); }
      }
    }

    // ---- conv2 (32->64, k=3, pad 1) + sign ----
    {
      const u32 w2m = g_w2b[lane * 3 + 1];
      const u64 pk = (u64)g_w2b[lane * 3 + 0] | ((u64)g_w2b[lane * 3 + 2] << 32);
      const u64 pkL = pk & 0xFFFFFFFFULL, pkH = pk & 0xFFFFFFFF00000000ULL;
      const int s2 = g_s2[lane];
      const int D96 = 96 - s2, D64 = 64 - s2;
      const u64 fl2 = g_flip2;
      const int p0 = half * 96;
      u32 a0 = (p0 > 0) ? W.p1s[p0 - 1] : 0u;   // value dead at w==0
      u32 a1 = W.p1s[p0];
      u32 a2 = W.p1s[p0 + 1];
      #pragma unroll 4
      for (int it = 0; it < 96; ++it) {
        int p = p0 + it, w = it & 31;
        int P = __popc(a1 ^ w2m);
        int pred;
        if (w == 0) {
          P += __popcll((((u64)a2) << 32) ^ pkH);
          pred = 2 * P <= D64;
        } else if (w == 31) {
          P += __popcll(((u64)a0) ^ pkL);
          pred = 2 * P <= D64;
        } else {
          P += __popcll(((((u64)a2) << 32) | a0) ^ pk);
          pred = 2 * P <= D96;
        }
        u64 mm = __ballot(pred) ^ fl2;
        if (lane == 0) W.c2s[p] = mm;
        a0 = a1; a1 = a2; a2 = W.p1s[p + 2];    // overrun values dead
      }
    }

    // ---- conv3 (64->128, k=3, pad 1) + sign + pool ----
    {
      const u64 wl0 = g_w3b[lane * 3 + 0], wl1 = g_w3b[lane * 3 + 1], wl2 = g_w3b[lane * 3 + 2];
      const u64 wh0 = g_w3b[(64 + lane) * 3 + 0], wh1 = g_w3b[(64 + lane) * 3 + 1], wh2 = g_w3b[(64 + lane) * 3 + 2];
      const int sa = g_s3[lane], sb = g_s3[64 + lane];
      const int Da192 = 192 - sa, Da128 = 128 - sa;
      const int Db192 = 192 - sb, Db128 = 128 - sb;
      const int f3a = (int)((g_flip3[0] >> lane) & 1);
      const int f3b = (int)((g_flip3[1] >> lane) & 1);
      #pragma unroll 2
      for (int it = 0; it < 48; ++it) {
        int pt = half * 48 + it;             // pooled pos (row*16+pw)
        int pw = pt & 15;
        int base = (pt >> 4) * 32 + 2 * pw;
        u64 Bm = W.c2s[base], Cm = W.c2s[base + 1];
        int predA, predB;
        if (pw == 0) {
          u64 Dm = W.c2s[base + 2];
          int P0a = __popcll(Bm ^ wl1) + __popcll(Cm ^ wl2);
          int P1a = __popcll(Bm ^ wl0) + __popcll(Cm ^ wl1) + __popcll(Dm ^ wl2);
          int P0b = __popcll(Bm ^ wh1) + __popcll(Cm ^ wh2);
          int P1b = __popcll(Bm ^ wh0) + __popcll(Cm ^ wh1) + __popcll(Dm ^ wh2);
          predA = ((2 * P0a <= Da128) ^ f3a) | ((2 * P1a <= Da192) ^ f3a);
          predB = ((2 * P0b <= Db128) ^ f3b) | ((2 * P1b <= Db192) ^ f3b);
        } else if (pw == 15) {
          u64 Am = W.c2s[base - 1];
          int P0a = __popcll(Am ^ wl0) + __popcll(Bm ^ wl1) + __popcll(Cm ^ wl2);
          int P1a = __popcll(Bm ^ wl0) + __popcll(Cm ^ wl1);
          int P0b = __popcll(Am ^ wh0) + __popcll(Bm ^ wh1) + __popcll(Cm ^ wh2);
          int P1b = __popcll(Bm ^ wh0) + __popcll(Cm ^ wh1);
          predA = ((2 * P0a <= Da192) ^ f3a) | ((2 * P1a <= Da128) ^ f3a);
          predB = ((2 * P0b <= Db192) ^ f3b) | ((2 * P1b <= Db128) ^ f3b);
        } else {
          u64 Am = W.c2s[base - 1], Dm = W.c2s[base + 2];
          int P0a = __popcll(Am ^ wl0) + __popcll(Bm ^ wl1) + __popcll(Cm ^ wl2);
          int P1a = __popcll(Bm ^ wl0) + __popcll(Cm ^ wl1) + __popcll(Dm ^ wl2);
          int P0b = __popcll(Am ^ wh0) + __popcll(Bm ^ wh1) + __popcll(Cm ^ wh2);
          int P1b = __popcll(Bm ^ wh0) + __popcll(Cm ^ wh1) + __popcll(Dm ^ wh2);
          predA = ((2 * P0a <= Da192) ^ f3a) | ((2 * P1a <= Da192) ^ f3a);
          predB = ((2 * P0b <= Db192) ^ f3b) | ((2 * P1b <= Db192) ^ f3b);
        }
        u64 m0 = __ballot(predA);
        u64 m1 = __ballot(predB);
        if (lane == 0) { W.p3s[2 * pt] = m0; W.p3s[2 * pt + 1] = m1; }
      }
    }
  }

  __syncthreads();   // conv4 mixes rows across the two waves

  if (active) {
    // ---- conv4 (128->128, k=(6,1)) + sign — split by output-channel half ----
    u64 wv4[12];
    #pragma unroll
    for (int h = 0; h < 6; ++h) {
      wv4[h * 2 + 0] = g_w4b[((half * 64 + lane) * 6 + h) * 2 + 0];
      wv4[h * 2 + 1] = g_w4b[((half * 64 + lane) * 6 + h) * 2 + 1];
    }
    const int Dc = 768 - g_s4[half * 64 + lane];
    const u64 fl4 = half ? g_flip4[1] : g_flip4[0];
    for (int w = 0; w < 16; ++w) {
      int acc = 0;
      #pragma unroll
      for (int h = 0; h < 6; ++h) {
        u64 aL = W.p3s[(h * 16 + w) * 2];
        u64 aH = W.p3s[(h * 16 + w) * 2 + 1];
        acc += __popcll(aL ^ wv4[h * 2]) + __popcll(aH ^ wv4[h * 2 + 1]);
      }
      u64 m = __ballot(2 * acc <= Dc) ^ fl4;
      if (lane == 0) W.c4s[2 * w + half] = m;
    }
  }

  __syncthreads();   // FC reads both channel halves

  if (active && half == 0) {
    // ---- FC: sign(h) . sign(wfc)^T + bfc  (shuffle reduce) ----
    const int k = lane & 31, hf = lane >> 5;
    u64 hw = W.c4s[(k & 15) * 2 + (k >> 4)];
    #pragma unroll
    for (int it = 0; it < 3; ++it) {
      int j = 2 * it + hf;
      int pc = __popcll(hw ^ g_wfcb[j * 32 + k]);
      pc += __shfl_xor(pc, 16);
      pc += __shfl_xor(pc, 8);
      pc += __shfl_xor(pc, 4);
      pc += __shfl_xor(pc, 2);
      pc += __shfl_xor(pc, 1);
      if (k == 0)
        out[(size_t)n * 6 + j] = __fadd_rn((float)(2048 - 2 * pc), g_bfc[j]);
    }
  }
}

// ------------------------------ launch --------------------------------------
extern "C" void kernel_launch(void* const* d_in, const int* in_sizes, int n_in,
                              void* d_out, int out_size, void* d_ws, size_t ws_size,
                              hipStream_t stream) {
  (void)d_ws; (void)ws_size; (void)n_in;
  Ptrs P;
  for (int i = 0; i < 27; ++i) P.p[i] = (const float*)d_in[i];

  hipLaunchKernelGGL(prepack_kernel, dim3(11), dim3(256), 0, stream, P);

  const float* x = (const float*)d_in[0];
  float* out = (float*)d_out;
  int B = in_sizes[0] / 768;                 // 4096
  hipLaunchKernelGGL(fused_kernel, dim3((B + 1) / 2), dim3(256), 0, stream, x, out, B);
}

// Round 7
// 84.364 us; speedup vs baseline: 2.8342x; 1.2622x over previous
//
#include <hip/hip_runtime.h>

typedef unsigned long long u64;
typedef unsigned int u32;

// ---------------- packed weights / integer thresholds (device globals) ------
__device__ u32 g_w1b[32];                 // 9 taps in low bits
__device__ u32 g_w2b[64 * 3];             // [c][k], bit = cin (0..31)
__device__ u64 g_w3b[128 * 3];            // [c][k], bit = cin (0..63)
__device__ u64 g_w4b[128 * 6 * 2];        // [c][h][hi], bit l = cin hi*64+l
__device__ u64 g_wfcb[6 * 32];            // [j][k]: w=k%16, hi=k/16, bit l -> i=(hi*64+l)*16+w
__device__ float g_bfc[6];

__device__ int g_s1[32], g_s2[64], g_s3[128], g_s4[128];   // integer S-thresholds
__device__ u64 g_flip1, g_flip2, g_flip3[2], g_flip4[2];   // per-layer flip masks

struct Ptrs { const float* p[27]; };

// exact f32 op order of the np reference: y = ((S + b) * inv) + t, no FMA
__device__ __forceinline__ int predS(int S, float b, float inv, float t) {
  float hv = __fadd_rn((float)S, b);
  float y = __fadd_rn(__fmul_rn(hv, inv), t);
  return y > 0.0f;
}

__device__ __forceinline__ void bn_fold(float b, float g, float be, float m, float v,
                                        float* ob, float* oinv, float* ot) {
  double iv = (double)g * (1.0 / sqrt((double)v + 1e-5));
  float invf = (float)iv;
  *ob = b;
  *oinv = invf;
  *ot = __fadd_rn(be, -__fmul_rn(m, invf));
}

// pred(S) == (S >= smin) XOR flip, exactly, for all integer S in range.
__device__ __forceinline__ void find_thr(float bias, float g, float be, float m, float v,
                                         int* smin, int* flip) {
  float b, inv, t;
  bn_fold(bias, g, be, m, v, &b, &inv, &t);
  int pl = predS(-2048, b, inv, t), ph = predS(2048, b, inv, t);
  if (pl && ph) { *smin = -4096; *flip = 0; }
  else if (!pl && !ph) { *smin = 4096; *flip = 0; }
  else if (!pl && ph) {
    int lo = -2048, hi = 2048;
    while (hi - lo > 1) { int md = (lo + hi) >> 1; if (predS(md, b, inv, t)) hi = md; else lo = md; }
    *smin = hi; *flip = 0;
  } else {
    int lo = -2048, hi = 2048;
    while (hi - lo > 1) { int md = (lo + hi) >> 1; if (predS(md, b, inv, t)) lo = md; else hi = md; }
    *smin = lo + 1; *flip = 1;
  }
}

// -------------------------- weight prepack ---------------------------------
__global__ __launch_bounds__(256) void prepack_kernel(Ptrs P) {
  int tid = threadIdx.x;
  int gid = blockIdx.x * 256 + tid;
  if (gid < 32) {
    int c = gid, smin, flip;
    find_thr(P.p[2][c], P.p[3][c], P.p[4][c], P.p[5][c], P.p[6][c], &smin, &flip);
    g_s1[c] = smin;
    u64 fl = __ballot(flip != 0);
    if (c == 0) g_flip1 = (fl & 0xFFFFFFFFULL) | (fl << 32);
  } else if (gid >= 64 && gid < 128) {
    int c = gid - 64, smin, flip;
    find_thr(P.p[8][c], P.p[9][c], P.p[10][c], P.p[11][c], P.p[12][c], &smin, &flip);
    g_s2[c] = smin;
    u64 fl = __ballot(flip != 0);
    if (c == 0) g_flip2 = fl;
  } else if (gid >= 128 && gid < 256) {
    int c = gid - 128, smin, flip;
    find_thr(P.p[14][c], P.p[15][c], P.p[16][c], P.p[17][c], P.p[18][c], &smin, &flip);
    g_s3[c] = smin;
    u64 fl = __ballot(flip != 0);
    if ((c & 63) == 0) g_flip3[c >> 6] = fl;
  } else if (gid >= 256 && gid < 384) {
    int c = gid - 256, smin, flip;
    find_thr(P.p[20][c], P.p[21][c], P.p[22][c], P.p[23][c], P.p[24][c], &smin, &flip);
    g_s4[c] = smin;
    u64 fl = __ballot(flip != 0);
    if ((c & 63) == 0) g_flip4[c >> 6] = fl;
  } else if (gid >= 384 && gid < 416) {
    int c = gid - 384;
    u32 b = 0;
    for (int k = 0; k < 9; ++k)
      if (P.p[1][c * 9 + k] > 0.0f) b |= (1u << k);
    g_w1b[c] = b;
  } else if (gid >= 416 && gid < 422) {
    g_bfc[gid - 416] = P.p[26][gid - 416];
  } else if (gid >= 512 && gid < 704) {
    int idx = gid - 512;
    int c = idx / 3, k = idx % 3;
    u32 b = 0;
    for (int cin = 0; cin < 32; ++cin)
      if (P.p[7][(c * 32 + cin) * 3 + k] > 0.0f) b |= (1u << cin);
    g_w2b[c * 3 + k] = b;
  } else if (gid >= 704 && gid < 1088) {
    int idx = gid - 704;
    int c = idx / 3, k = idx % 3;
    u64 b = 0;
    for (int cin = 0; cin < 64; ++cin)
      if (P.p[13][(c * 64 + cin) * 3 + k] > 0.0f) b |= (1ull << cin);
    g_w3b[c * 3 + k] = b;
  } else if (gid >= 1088 && gid < 2624) {
    int idx = gid - 1088;
    int c = idx / 12, r = idx % 12, h = r >> 1, hi = r & 1;
    u64 b = 0;
    for (int l = 0; l < 64; ++l) {
      int cin = hi * 64 + l;
      if (P.p[19][(c * 128 + cin) * 6 + h] > 0.0f) b |= (1ull << l);
    }
    g_w4b[(c * 6 + h) * 2 + hi] = b;
  } else if (gid >= 2624 && gid < 2816) {
    int idx = gid - 2624;
    int j = idx / 32, k = idx % 32;
    int w = k & 15, hi = k >> 4;
    u64 b = 0;
    for (int l = 0; l < 64; ++l) {
      int i = (hi * 64 + l) * 16 + w;
      if (P.p[25][j * 2048 + i] > 0.0f) b |= (1ull << l);
    }
    g_wfcb[j * 32 + k] = b;
  }
}

// ----------------------- fused binary network ------------------------------
// TWO WAVES PER IMAGE (rows 0-2 / 3-5). conv1->conv2->conv3 processed one row
// at a time entirely in wave-uniform registers (ballot results are SGPRs).
// Only conv3's pooled output (consumed cross-wave by conv4) goes to LDS.
struct WaveMem {
  alignas(16) u64 p3s[192];   // conv3+pool out (h*16+pw)*2+chanhalf
  u64 c4s[32];                // conv4 out w*2+chanhalf
};

__global__ __launch_bounds__(256) void fused_kernel(const float* __restrict__ x,
                                                    float* __restrict__ out, int B) {
  const int tid = threadIdx.x;
  const int lane = tid & 63;
  const int wave = tid >> 6;         // 0..3
  const int img = wave >> 1;         // 0..1 within block
  const int half = wave & 1;         // row-half of the image
  const int n = blockIdx.x * 2 + img;
  const bool active = (n < B);

  __shared__ WaveMem wm[2];
  WaveMem& W = wm[img];
  const float* xi = x + (size_t)n * 768;

  if (active) {
    // ---- per-lane constants for conv1..conv3 ----
    const int c1 = lane & 31;
    const bool isSub1 = (lane >= 32);
    const u32 wv = g_w1b[c1];
    const u32 wv2 = wv << 2;
    const int s1v = g_s1[c1];
    const int D0i = (9 - s1v) >> 1;
    const int D0a = (5 - s1v + 2 * __popc(wv & 0x00F)) >> 1;
    const int D0b = (8 - s1v + 2 * __popc(wv & 0x100)) >> 1;
    const int D1a = (7 - s1v + 2 * __popc(wv & 0x003)) >> 1;
    const int D1b = (6 - s1v + 2 * __popc(wv & 0x1C0)) >> 1;
    const u64 fl1 = g_flip1;

    const u32 w0m = g_w2b[lane * 3 + 0];
    const u32 w1m = g_w2b[lane * 3 + 1];
    const u32 w2m = g_w2b[lane * 3 + 2];
    const int s2v = g_s2[lane];
    const int D96h = (96 - s2v) >> 1, D64h = (64 - s2v) >> 1;
    const u64 fl2 = g_flip2;

    const u32* w3p = (const u32*)g_w3b;
    const u32 wl0l = w3p[(lane * 3 + 0) * 2], wl0h = w3p[(lane * 3 + 0) * 2 + 1];
    const u32 wl1l = w3p[(lane * 3 + 1) * 2], wl1h = w3p[(lane * 3 + 1) * 2 + 1];
    const u32 wl2l = w3p[(lane * 3 + 2) * 2], wl2h = w3p[(lane * 3 + 2) * 2 + 1];
    const u32 wh0l = w3p[((64 + lane) * 3 + 0) * 2], wh0h = w3p[((64 + lane) * 3 + 0) * 2 + 1];
    const u32 wh1l = w3p[((64 + lane) * 3 + 1) * 2], wh1h = w3p[((64 + lane) * 3 + 1) * 2 + 1];
    const u32 wh2l = w3p[((64 + lane) * 3 + 2) * 2], wh2h = w3p[((64 + lane) * 3 + 2) * 2 + 1];
    const int sa = g_s3[lane], sb = g_s3[64 + lane];
    const int Da192h = (192 - sa) >> 1, Da128h = (128 - sa) >> 1;
    const int Db192h = (192 - sb) >> 1, Db128h = (128 - sb) >> 1;
    const u64 f3a = g_flip3[0], f3b = g_flip3[1];

    // ---- process this wave's 3 rows ----
    #pragma unroll
    for (int hl = 0; hl < 3; ++hl) {
      const int h = half * 3 + hl;
      // stage A: binarize row into padded (<<4) form; all wave-uniform
      float v0 = xi[h * 128 + lane];
      float v1 = xi[h * 128 + 64 + lane];
      u64 m0 = __ballot(v0 > 0.0f);
      u64 m1 = __ballot(v1 > 0.0f);
      const u64 ra = m0 << 4;
      const u64 rb = (m0 >> 60) | (m1 << 4);
      const u64 rc = m1 >> 60;

      // conv1 + sign + pool: 16 ballots -> a64[j] covers pooled pos 2j,2j+1
      u64 a64[16];
      #pragma unroll
      for (int j = 0; j < 16; ++j) {
        u64 lo = (j < 8) ? ra : rb;
        u64 hi = (j < 8) ? rb : rc;
        const int sh = (8 * j) & 63;
        u64 Wq = (lo >> sh) | ((hi << 1) << (63 - sh));   // 15-bit superwindow
        u32 W0 = (u32)Wq & 0x7FF;
        u32 W1 = ((u32)Wq >> 4) & 0x7FF;
        u32 Wv = isSub1 ? W1 : W0;       // sub0 half: pooled 2j; sub1: 2j+1
        int P0 = __popc((Wv ^ wv) & 0x1FF);
        int P1 = __popc((Wv ^ wv2) & 0x7FC);
        int D0 = D0i, D1 = D0i;
        if (j == 0)  { D0 = isSub1 ? D0i : D0a; D1 = isSub1 ? D0i : D1a; }
        if (j == 15) { D0 = isSub1 ? D0b : D0i; D1 = isSub1 ? D1b : D0i; }
        a64[j] = (__ballot(P0 <= D0) ^ fl1) | (__ballot(P1 <= D1) ^ fl1);
      }

      // u32 view of pooled row (static index -> SALU extract)
      auto AW = [&](int w) -> u32 {
        u64 v = a64[w >> 1];
        return (w & 1) ? (u32)(v >> 32) : (u32)v;
      };
      // conv2 (32->64, k=3, pad1) + sign: one ballot per position
      auto CONV2 = [&](int w, u32 am, u32 ac, u32 ap) -> u64 {
        int P, D;
        if (w == 0)       { P = __popc(ac ^ w1m) + __popc(ap ^ w2m); D = D64h; }
        else if (w == 31) { P = __popc(am ^ w0m) + __popc(ac ^ w1m); D = D64h; }
        else { P = __popc(am ^ w0m) + __popc(ac ^ w1m) + __popc(ap ^ w2m); D = D96h; }
        return __ballot(P <= D) ^ fl2;
      };
      // conv3 (64->128, k=3, pad1) + sign + pool; kind: 0=pw0, 1=mid, 2=pw15
      auto CONV3 = [&](int kind, u64 Au, u64 Bu, u64 Cu, u64 Du, int pt) {
        u32 Al = (u32)Au, Ah = (u32)(Au >> 32);
        u32 Bl = (u32)Bu, Bh = (u32)(Bu >> 32);
        u32 Cl = (u32)Cu, Ch = (u32)(Cu >> 32);
        u32 Dl = (u32)Du, Dh = (u32)(Du >> 32);
        int P0a, P1a, P0b, P1b, E0a, E1a, E0b, E1b;
        if (kind == 0) {       // out0 short (B,C taps1,2), out1 full (B,C,D)
          P0a = __popc(Bl^wl1l)+__popc(Bh^wl1h)+__popc(Cl^wl2l)+__popc(Ch^wl2h);
          P1a = __popc(Bl^wl0l)+__popc(Bh^wl0h)+__popc(Cl^wl1l)+__popc(Ch^wl1h)
              + __popc(Dl^wl2l)+__popc(Dh^wl2h);
          P0b = __popc(Bl^wh1l)+__popc(Bh^wh1h)+__popc(Cl^wh2l)+__popc(Ch^wh2h);
          P1b = __popc(Bl^wh0l)+__popc(Bh^wh0h)+__popc(Cl^wh1l)+__popc(Ch^wh1h)
              + __popc(Dl^wh2l)+__popc(Dh^wh2h);
          E0a = Da128h; E1a = Da192h; E0b = Db128h; E1b = Db192h;
        } else if (kind == 2) { // out0 full (A,B,C), out1 short (B,C taps0,1)
          P0a = __popc(Al^wl0l)+__popc(Ah^wl0h)+__popc(Bl^wl1l)+__popc(Bh^wl1h)
              + __popc(Cl^wl2l)+__popc(Ch^wl2h);
          P1a = __popc(Bl^wl0l)+__popc(Bh^wl0h)+__popc(Cl^wl1l)+__popc(Ch^wl1h);
          P0b = __popc(Al^wh0l)+__popc(Ah^wh0h)+__popc(Bl^wh1l)+__popc(Bh^wh1h)
              + __popc(Cl^wh2l)+__popc(Ch^wh2h);
          P1b = __popc(Bl^wh0l)+__popc(Bh^wh0h)+__popc(Cl^wh1l)+__popc(Ch^wh1h);
          E0a = Da192h; E1a = Da128h; E0b = Db192h; E1b = Db128h;
        } else {
          P0a = __popc(Al^wl0l)+__popc(Ah^wl0h)+__popc(Bl^wl1l)+__popc(Bh^wl1h)
              + __popc(Cl^wl2l)+__popc(Ch^wl2h);
          P1a = __popc(Bl^wl0l)+__popc(Bh^wl0h)+__popc(Cl^wl1l)+__popc(Ch^wl1h)
              + __popc(Dl^wl2l)+__popc(Dh^wl2h);
          P0b = __popc(Al^wh0l)+__popc(Ah^wh0h)+__popc(Bl^wh1l)+__popc(Bh^wh1h)
              + __popc(Cl^wh2l)+__popc(Ch^wh2h);
          P1b = __popc(Bl^wh0l)+__popc(Bh^wh0h)+__popc(Cl^wh1l)+__popc(Ch^wh1h)
              + __popc(Dl^wh2l)+__popc(Dh^wh2h);
          E0a = Da192h; E1a = Da192h; E0b = Db192h; E1b = Db192h;
        }
        u64 mm0 = (__ballot(P0a <= E0a) ^ f3a) | (__ballot(P1a <= E1a) ^ f3a);
        u64 mm1 = (__ballot(P0b <= E0b) ^ f3b) | (__ballot(P1b <= E1b) ^ f3b);
        if (lane == 0) { W.p3s[2 * pt] = mm0; W.p3s[2 * pt + 1] = mm1; }
      };

      const int pt0 = h * 16;
      // software-pipelined conv2 -> conv3 over the row
      u64 cw0 = CONV2(0, AW(0), AW(0), AW(1));
      u64 cw1 = CONV2(1, AW(0), AW(1), AW(2));
      u64 cw2 = CONV2(2, AW(1), AW(2), AW(3));
      CONV3(0, cw0, cw0, cw1, cw2, pt0);           // pw=0: B=c2[0],C=c2[1],D=c2[2]
      u64 Ar = cw1, Br = cw2;                      // c2[2pw-1], c2[2pw] for pw=1
      #pragma unroll
      for (int pw = 1; pw <= 14; ++pw) {
        u64 Cr = CONV2(2 * pw + 1, AW(2 * pw), AW(2 * pw + 1), AW(2 * pw + 2));
        u64 Dr = CONV2(2 * pw + 2, AW(2 * pw + 1), AW(2 * pw + 2), AW(2 * pw + 3));
        CONV3(1, Ar, Br, Cr, Dr, pt0 + pw);
        Ar = Cr; Br = Dr;
      }
      u64 C15 = CONV2(31, AW(30), AW(31), AW(31));
      CONV3(2, Ar, Br, C15, C15, pt0 + 15);        // pw=15: A=c2[29],B=c2[30],C=c2[31]
    }
  }

  __syncthreads();   // conv4 mixes rows across the two waves

  if (active) {
    // ---- conv4 (128->128, k=(6,1)) + sign — split by output-channel half ----
    const u32* w4 = (const u32*)g_w4b;
    const int c = half * 64 + lane;
    u32 wt[24];
    #pragma unroll
    for (int h = 0; h < 6; ++h) {
      wt[h * 4 + 0] = w4[(c * 6 + h) * 4 + 0];
      wt[h * 4 + 1] = w4[(c * 6 + h) * 4 + 1];
      wt[h * 4 + 2] = w4[(c * 6 + h) * 4 + 2];
      wt[h * 4 + 3] = w4[(c * 6 + h) * 4 + 3];
    }
    const int Dch = (768 - g_s4[c]) >> 1;
    const u64 fl4 = half ? g_flip4[1] : g_flip4[0];
    #pragma unroll 2
    for (int w = 0; w < 16; ++w) {
      int acc = 0;
      #pragma unroll
      for (int h = 0; h < 6; ++h) {
        const u32* p = (const u32*)&W.p3s[(h * 16 + w) * 2];
        acc += __popc(p[0] ^ wt[h * 4 + 0]) + __popc(p[1] ^ wt[h * 4 + 1])
             + __popc(p[2] ^ wt[h * 4 + 2]) + __popc(p[3] ^ wt[h * 4 + 3]);
      }
      u64 m = __ballot(acc <= Dch) ^ fl4;
      if (lane == 0) W.c4s[2 * w + half] = m;
    }
  }

  __syncthreads();   // FC reads both channel halves

  if (active && half == 0) {
    // ---- FC: sign(h) . sign(wfc)^T + bfc  (shuffle reduce) ----
    const int k = lane & 31, hf = lane >> 5;
    u64 hw = W.c4s[(k & 15) * 2 + (k >> 4)];
    #pragma unroll
    for (int it = 0; it < 3; ++it) {
      int j = 2 * it + hf;
      int pc = __popcll(hw ^ g_wfcb[j * 32 + k]);
      pc += __shfl_xor(pc, 16);
      pc += __shfl_xor(pc, 8);
      pc += __shfl_xor(pc, 4);
      pc += __shfl_xor(pc, 2);
      pc += __shfl_xor(pc, 1);
      if (k == 0)
        out[(size_t)n * 6 + j] = __fadd_rn((float)(2048 - 2 * pc), g_bfc[j]);
    }
  }
}

// ------------------------------ launch --------------------------------------
extern "C" void kernel_launch(void* const* d_in, const int* in_sizes, int n_in,
                              void* d_out, int out_size, void* d_ws, size_t ws_size,
                              hipStream_t stream) {
  (void)d_ws; (void)ws_size; (void)n_in;
  Ptrs P;
  for (int i = 0; i < 27; ++i) P.p[i] = (const float*)d_in[i];

  hipLaunchKernelGGL(prepack_kernel, dim3(11), dim3(256), 0, stream, P);

  const float* x = (const float*)d_in[0];
  float* out = (float*)d_out;
  int B = in_sizes[0] / 768;                 // 4096
  hipLaunchKernelGGL(fused_kernel, dim3((B + 1) / 2), dim3(256), 0, stream, x, out, B);
}